// Round 1
// baseline (1023.441 us; speedup 1.0000x reference)
//
#include <hip/hip_runtime.h>
#include <math.h>

#define N_NODES 100000
#define DIM 128
#define NH 8
#define NC 16
#define E_EDGES 400000
#define LN_EPS 1e-3f

// ---------------- Kernel 1: fused k/m/q projections ----------------
__global__ __launch_bounds__(128) void proj_kernel(
    const float* __restrict__ x,
    const float* __restrict__ Wk, const float* __restrict__ bk,
    const float* __restrict__ Wm, const float* __restrict__ bm,
    const float* __restrict__ Wq, const float* __restrict__ bq,
    float* __restrict__ kout, float* __restrict__ mout, float* __restrict__ qout)
{
    const int ROWS = 16;
    __shared__ float xs[ROWS][DIM];
    const int block_row = blockIdx.x * ROWS;
    const int j = threadIdx.x;

    #pragma unroll
    for (int r = 0; r < ROWS; ++r) {
        int row = block_row + r;
        xs[r][j] = (row < N_NODES) ? x[(size_t)row * DIM + j] : 0.f;
    }
    __syncthreads();

    float acck[ROWS], accm[ROWS], accq[ROWS];
    #pragma unroll
    for (int r = 0; r < ROWS; ++r) { acck[r] = 0.f; accm[r] = 0.f; accq[r] = 0.f; }

    for (int d = 0; d < DIM; ++d) {
        float wk = Wk[d * DIM + j];
        float wm = Wm[d * DIM + j];
        float wq = Wq[d * DIM + j];
        #pragma unroll
        for (int r = 0; r < ROWS; ++r) {
            float xv = xs[r][d];
            acck[r] = fmaf(xv, wk, acck[r]);
            accm[r] = fmaf(xv, wm, accm[r]);
            accq[r] = fmaf(xv, wq, accq[r]);
        }
    }

    float bkj = bk[j], bmj = bm[j], bqj = bq[j];
    #pragma unroll
    for (int r = 0; r < ROWS; ++r) {
        int row = block_row + r;
        if (row < N_NODES) {
            kout[(size_t)row * DIM + j] = acck[r] + bkj;
            mout[(size_t)row * DIM + j] = accm[r] + bmj;
            qout[(size_t)row * DIM + j] = accq[r] + bqj;
        }
    }
}

// ---------------- Kernel 2: per-edge scores + message pooling ----------------
// 256 threads = 2 edge slots x 128 threads; thread t = h*16 + l.
__global__ __launch_bounds__(256) void edge_kernel(
    const float* __restrict__ kbuf, const float* __restrict__ mbuf, const float* __restrict__ qbuf,
    const int* __restrict__ src0, const int* __restrict__ dst0,
    const int* __restrict__ src1, const int* __restrict__ dst1,
    const float* __restrict__ Watt0, const float* __restrict__ Wmsg0,
    const float* __restrict__ Watt1, const float* __restrict__ Wmsg1,
    const float* __restrict__ prior0, const float* __restrict__ prior1,
    float* __restrict__ pooled, float* __restrict__ denom)
{
    __shared__ float wa0[NH * NC * NC], wm0[NH * NC * NC];
    __shared__ float wa1[NH * NC * NC], wm1[NH * NC * NC];
    __shared__ float ks[2][DIM], ms[2][DIM], qs[2][DIM];
    __shared__ float pr[2][NH];

    // Stage weights in LDS, layout [kk][h][l] (index = kk*128 + h*16 + l)
    // so that consecutive threads read consecutive words (conflict-free).
    for (int i = threadIdx.x; i < NH * NC * NC; i += 256) {
        int kk = i >> 7;           // 0..15
        int rest = i & 127;        // h*16 + l
        int h = rest >> 4, l = rest & 15;
        int g = (h * NC + kk) * NC + l;
        wa0[i] = Watt0[g]; wm0[i] = Wmsg0[g];
        wa1[i] = Watt1[g]; wm1[i] = Wmsg1[g];
    }
    if (threadIdx.x < NH) {
        pr[0][threadIdx.x] = prior0[threadIdx.x];
        pr[1][threadIdx.x] = prior1[threadIdx.x];
    }
    __syncthreads();

    const int slot = threadIdx.x >> 7;      // 0 or 1
    const int t = threadIdx.x & 127;        // h*16 + l
    const int h = t >> 4, l = t & 15;
    const float scale = 0.25f;              // 1/sqrt(16)

    const int total = 2 * E_EDGES;
    for (int base = blockIdx.x * 2; base < total; base += gridDim.x * 2) {
        int e = base + slot;
        bool valid = (e < total);
        int set = 0, ee = e, dI = 0;
        if (valid) {
            if (ee >= E_EDGES) { set = 1; ee -= E_EDGES; }
            int sI = set ? src1[ee] : src0[ee];
            dI     = set ? dst1[ee] : dst0[ee];
            ks[slot][t] = kbuf[(size_t)sI * DIM + t];
            ms[slot][t] = mbuf[(size_t)sI * DIM + t];
            qs[slot][t] = qbuf[(size_t)dI * DIM + t];
        }
        __syncthreads();
        if (valid) {
            const float* wa = set ? wa1 : wa0;
            const float* wm = set ? wm1 : wm0;
            float ke = 0.f, mg = 0.f;
            #pragma unroll
            for (int kk = 0; kk < NC; ++kk) {
                float kv = ks[slot][h * NC + kk];
                float mv = ms[slot][h * NC + kk];
                ke = fmaf(kv, wa[kk * DIM + t], ke);
                mg = fmaf(mv, wm[kk * DIM + t], mg);
            }
            float p = ke * qs[slot][t];
            // reduce over the 16 lanes of this head (groups aligned within wave64)
            p += __shfl_xor(p, 1, 64);
            p += __shfl_xor(p, 2, 64);
            p += __shfl_xor(p, 4, 64);
            p += __shfl_xor(p, 8, 64);
            float score = p * pr[set][h] * scale;
            float es = expf(score);   // no segment-max needed: |score| small
            atomicAdd(&pooled[(size_t)dI * DIM + t], es * mg);
            if (l == 0) atomicAdd(&denom[(size_t)dI * NH + h], es);
        }
        __syncthreads();
    }
}

// ---------------- Kernel 3: gelu -> GEMM(Wa) -> skip -> LayerNorm ----------------
__global__ __launch_bounds__(128) void final_kernel(
    const float* __restrict__ pooled, const float* __restrict__ denom,
    const float* __restrict__ x,
    const float* __restrict__ Wa, const float* __restrict__ ba,
    const float* __restrict__ skip, const float* __restrict__ gamma,
    const float* __restrict__ beta,
    float* __restrict__ out)
{
    const int ROWS = 16;
    __shared__ float gs[ROWS][DIM];
    __shared__ float hs[ROWS][DIM];
    const int block_row = blockIdx.x * ROWS;
    const int j = threadIdx.x;

    #pragma unroll
    for (int r = 0; r < ROWS; ++r) {
        int row = block_row + r;
        float g = 0.f;
        if (row < N_NODES) {
            float dh = denom[(size_t)row * NH + (j >> 4)];
            float p = pooled[(size_t)row * DIM + j];
            if (dh > 0.f) {
                float v = p / dh;
                g = 0.5f * v * (1.f + erff(v * 0.70710678118654752f));
            }
        }
        gs[r][j] = g;
    }
    __syncthreads();

    float acc[ROWS];
    #pragma unroll
    for (int r = 0; r < ROWS; ++r) acc[r] = 0.f;
    for (int d = 0; d < DIM; ++d) {
        float w = Wa[d * DIM + j];
        #pragma unroll
        for (int r = 0; r < ROWS; ++r) acc[r] = fmaf(gs[r][d], w, acc[r]);
    }

    float alpha = 1.f / (1.f + expf(-skip[0]));
    float baj = ba[j];
    #pragma unroll
    for (int r = 0; r < ROWS; ++r) {
        int row = block_row + r;
        float xv = (row < N_NODES) ? x[(size_t)row * DIM + j] : 0.f;
        hs[r][j] = alpha * (acc[r] + baj) + (1.f - alpha) * xv;
    }
    __syncthreads();

    // LayerNorm: wave w handles rows w, w+2, ... (each lane covers 2 columns)
    const int wave = j >> 6, lane = j & 63;
    float gam0 = gamma[lane], gam1 = gamma[lane + 64];
    float bet0 = beta[lane],  bet1 = beta[lane + 64];
    for (int r = wave; r < ROWS; r += 2) {
        int row = block_row + r;
        if (row >= N_NODES) break;
        float v0 = hs[r][lane], v1 = hs[r][lane + 64];
        float s = v0 + v1, s2 = v0 * v0 + v1 * v1;
        #pragma unroll
        for (int off = 1; off < 64; off <<= 1) {
            s  += __shfl_xor(s,  off, 64);
            s2 += __shfl_xor(s2, off, 64);
        }
        float mu = s * (1.f / 128.f);
        float var = s2 * (1.f / 128.f) - mu * mu;
        float rstd = rsqrtf(var + LN_EPS);
        out[(size_t)row * DIM + lane]      = (v0 - mu) * rstd * gam0 + bet0;
        out[(size_t)row * DIM + lane + 64] = (v1 - mu) * rstd * gam1 + bet1;
    }
}

extern "C" void kernel_launch(void* const* d_in, const int* in_sizes, int n_in,
                              void* d_out, int out_size, void* d_ws, size_t ws_size,
                              hipStream_t stream) {
    const float* x     = (const float*)d_in[0];
    const int*   src0  = (const int*)d_in[1];
    const int*   dst0  = (const int*)d_in[2];
    const int*   src1  = (const int*)d_in[3];
    const int*   dst1  = (const int*)d_in[4];
    const float* Wk    = (const float*)d_in[5];
    const float* bk    = (const float*)d_in[6];
    const float* Wm    = (const float*)d_in[7];
    const float* bm    = (const float*)d_in[8];
    const float* Wq    = (const float*)d_in[9];
    const float* bq    = (const float*)d_in[10];
    const float* Wa    = (const float*)d_in[11];
    const float* ba    = (const float*)d_in[12];
    const float* Watt0 = (const float*)d_in[13];
    const float* Wmsg0 = (const float*)d_in[14];
    const float* Watt1 = (const float*)d_in[15];
    const float* Wmsg1 = (const float*)d_in[16];
    const float* prior0= (const float*)d_in[17];
    const float* prior1= (const float*)d_in[18];
    const float* skip  = (const float*)d_in[19];
    const float* gamma = (const float*)d_in[20];
    const float* beta  = (const float*)d_in[21];
    float* out = (float*)d_out;

    const size_t nd = (size_t)N_NODES * DIM;
    float* ws = (float*)d_ws;
    float* kbuf   = ws;
    float* mbuf   = kbuf + nd;
    float* qbuf   = mbuf + nd;
    float* pooled = qbuf + nd;
    float* denomb = pooled + nd;

    // zero accumulators (pooled + denom are contiguous)
    hipMemsetAsync(pooled, 0, (nd + (size_t)N_NODES * NH) * sizeof(float), stream);

    dim3 blk(128), grd((N_NODES + 15) / 16);
    proj_kernel<<<grd, blk, 0, stream>>>(x, Wk, bk, Wm, bm, Wq, bq, kbuf, mbuf, qbuf);
    edge_kernel<<<dim3(8192), dim3(256), 0, stream>>>(
        kbuf, mbuf, qbuf, src0, dst0, src1, dst1,
        Watt0, Wmsg0, Watt1, Wmsg1, prior0, prior1, pooled, denomb);
    final_kernel<<<grd, blk, 0, stream>>>(pooled, denomb, x, Wa, ba, skip, gamma, beta, out);
}

// Round 3
// 909.800 us; speedup vs baseline: 1.1249x; 1.1249x over previous
//
#include <hip/hip_runtime.h>
#include <hip/hip_bf16.h>
#include <math.h>

#define N_NODES 100000
#define DIM 128
#define NH 8
#define NC 16
#define E_EDGES 400000
#define LN_EPS 1e-3f

// ---------------- Kernel 1: fused k/m/q projections + relation projections ----
// Outputs: q (N,128 fp32, in d_out), katt0/katt1 (N,128 fp32; k@Watt_s scaled
// by prior/sqrt(C)), mmsg0/mmsg1 (N,128 bf16; m@Wmsg_s).
__global__ __launch_bounds__(128) void proj_kernel(
    const float* __restrict__ x,
    const float* __restrict__ Wk, const float* __restrict__ bk,
    const float* __restrict__ Wm, const float* __restrict__ bm,
    const float* __restrict__ Wq, const float* __restrict__ bq,
    const float* __restrict__ Watt0, const float* __restrict__ Wmsg0,
    const float* __restrict__ Watt1, const float* __restrict__ Wmsg1,
    const float* __restrict__ prior0, const float* __restrict__ prior1,
    float* __restrict__ qout,
    float* __restrict__ katt0, float* __restrict__ katt1,
    __hip_bfloat16* __restrict__ mmsg0, __hip_bfloat16* __restrict__ mmsg1)
{
    const int ROWS = 16;
    __shared__ float xs[ROWS][DIM];
    __shared__ float ks[ROWS][DIM];
    __shared__ float ms[ROWS][DIM];
    const int block_row = blockIdx.x * ROWS;
    const int j = threadIdx.x;
    const int h = j >> 4, l = j & 15;

    #pragma unroll
    for (int r = 0; r < ROWS; ++r) {
        int row = block_row + r;
        xs[r][j] = (row < N_NODES) ? x[(size_t)row * DIM + j] : 0.f;
    }
    __syncthreads();

    float acck[ROWS], accm[ROWS], accq[ROWS];
    #pragma unroll
    for (int r = 0; r < ROWS; ++r) { acck[r] = 0.f; accm[r] = 0.f; accq[r] = 0.f; }

    for (int d = 0; d < DIM; ++d) {
        float wk = Wk[d * DIM + j];
        float wm = Wm[d * DIM + j];
        float wq = Wq[d * DIM + j];
        #pragma unroll
        for (int r = 0; r < ROWS; ++r) {
            float xv = xs[r][d];
            acck[r] = fmaf(xv, wk, acck[r]);
            accm[r] = fmaf(xv, wm, accm[r]);
            accq[r] = fmaf(xv, wq, accq[r]);
        }
    }

    const float bkj = bk[j], bmj = bm[j], bqj = bq[j];
    #pragma unroll
    for (int r = 0; r < ROWS; ++r) {
        int row = block_row + r;
        if (row < N_NODES) qout[(size_t)row * DIM + j] = accq[r] + bqj;
        ks[r][j] = acck[r] + bkj;
        ms[r][j] = accm[r] + bmj;
    }
    __syncthreads();

    // Per-head 16x16 relation projections. Thread j=(h,l) owns output column l
    // of head h; weight column stays in registers, rows broadcast from LDS.
    const float sc = 0.25f;  // 1/sqrt(16)
    {
        float w[NC];
        #pragma unroll
        for (int kk = 0; kk < NC; ++kk) w[kk] = Watt0[(h * NC + kk) * NC + l];
        float p = prior0[h] * sc;
        #pragma unroll
        for (int r = 0; r < ROWS; ++r) {
            int row = block_row + r;
            if (row >= N_NODES) break;
            float s = 0.f;
            #pragma unroll
            for (int kk = 0; kk < NC; ++kk) s = fmaf(ks[r][h * NC + kk], w[kk], s);
            katt0[(size_t)row * DIM + j] = s * p;
        }
    }
    {
        float w[NC];
        #pragma unroll
        for (int kk = 0; kk < NC; ++kk) w[kk] = Watt1[(h * NC + kk) * NC + l];
        float p = prior1[h] * sc;
        #pragma unroll
        for (int r = 0; r < ROWS; ++r) {
            int row = block_row + r;
            if (row >= N_NODES) break;
            float s = 0.f;
            #pragma unroll
            for (int kk = 0; kk < NC; ++kk) s = fmaf(ks[r][h * NC + kk], w[kk], s);
            katt1[(size_t)row * DIM + j] = s * p;
        }
    }
    {
        float w[NC];
        #pragma unroll
        for (int kk = 0; kk < NC; ++kk) w[kk] = Wmsg0[(h * NC + kk) * NC + l];
        #pragma unroll
        for (int r = 0; r < ROWS; ++r) {
            int row = block_row + r;
            if (row >= N_NODES) break;
            float s = 0.f;
            #pragma unroll
            for (int kk = 0; kk < NC; ++kk) s = fmaf(ms[r][h * NC + kk], w[kk], s);
            mmsg0[(size_t)row * DIM + j] = __float2bfloat16(s);
        }
    }
    {
        float w[NC];
        #pragma unroll
        for (int kk = 0; kk < NC; ++kk) w[kk] = Wmsg1[(h * NC + kk) * NC + l];
        #pragma unroll
        for (int r = 0; r < ROWS; ++r) {
            int row = block_row + r;
            if (row >= N_NODES) break;
            float s = 0.f;
            #pragma unroll
            for (int kk = 0; kk < NC; ++kk) s = fmaf(ms[r][h * NC + kk], w[kk], s);
            mmsg1[(size_t)row * DIM + j] = __float2bfloat16(s);
        }
    }
}

// ---------------- Kernel 2: per-edge score + pooling (no FMA, no LDS, no barriers)
// 256 threads = 2 edge slots x 128 threads; thread t = h*16 + l.
__global__ __launch_bounds__(256) void edge_kernel(
    const float* __restrict__ katt0, const float* __restrict__ katt1,
    const __hip_bfloat16* __restrict__ mmsg0, const __hip_bfloat16* __restrict__ mmsg1,
    const float* __restrict__ qbuf,
    const int* __restrict__ src0, const int* __restrict__ dst0,
    const int* __restrict__ src1, const int* __restrict__ dst1,
    float* __restrict__ pooled, float* __restrict__ denom)
{
    const int slot = threadIdx.x >> 7;      // 0 or 1
    const int t = threadIdx.x & 127;        // h*16 + l
    const int l = t & 15;

    const int total = 2 * E_EDGES;
    for (int e = blockIdx.x * 2 + slot; e < total; e += gridDim.x * 2) {
        int sI, dI;
        const float* ka;
        const __hip_bfloat16* mm;
        if (e < E_EDGES) {
            sI = src0[e]; dI = dst0[e]; ka = katt0; mm = mmsg0;
        } else {
            int ee = e - E_EDGES;
            sI = src1[ee]; dI = dst1[ee]; ka = katt1; mm = mmsg1;
        }
        float p = ka[(size_t)sI * DIM + t] * qbuf[(size_t)dI * DIM + t];
        p += __shfl_xor(p, 1, 64);
        p += __shfl_xor(p, 2, 64);
        p += __shfl_xor(p, 4, 64);
        p += __shfl_xor(p, 8, 64);
        float es = expf(p);                  // no segment-max: |score| small
        float mg = __bfloat162float(mm[(size_t)sI * DIM + t]);
        atomicAdd(&pooled[(size_t)dI * DIM + t], es * mg);
        if (l == 0) atomicAdd(&denom[(size_t)dI * NH + (t >> 4)], es);
    }
}

// ---------------- Kernel 3: gelu -> GEMM(Wa) -> skip -> LayerNorm ----------------
__global__ __launch_bounds__(128) void final_kernel(
    const float* __restrict__ pooled, const float* __restrict__ denom,
    const float* __restrict__ x,
    const float* __restrict__ Wa, const float* __restrict__ ba,
    const float* __restrict__ skip, const float* __restrict__ gamma,
    const float* __restrict__ beta,
    float* __restrict__ out)
{
    const int ROWS = 16;
    __shared__ float gs[ROWS][DIM];
    __shared__ float hs[ROWS][DIM];
    const int block_row = blockIdx.x * ROWS;
    const int j = threadIdx.x;

    #pragma unroll
    for (int r = 0; r < ROWS; ++r) {
        int row = block_row + r;
        float g = 0.f;
        if (row < N_NODES) {
            float dh = denom[(size_t)row * NH + (j >> 4)];
            float p = pooled[(size_t)row * DIM + j];
            if (dh > 0.f) {
                float v = p / dh;
                g = 0.5f * v * (1.f + erff(v * 0.70710678118654752f));
            }
        }
        gs[r][j] = g;
    }
    __syncthreads();

    float acc[ROWS];
    #pragma unroll
    for (int r = 0; r < ROWS; ++r) acc[r] = 0.f;
    for (int d = 0; d < DIM; ++d) {
        float w = Wa[d * DIM + j];
        #pragma unroll
        for (int r = 0; r < ROWS; ++r) acc[r] = fmaf(gs[r][d], w, acc[r]);
    }

    float alpha = 1.f / (1.f + expf(-skip[0]));
    float baj = ba[j];
    #pragma unroll
    for (int r = 0; r < ROWS; ++r) {
        int row = block_row + r;
        float xv = (row < N_NODES) ? x[(size_t)row * DIM + j] : 0.f;
        hs[r][j] = alpha * (acc[r] + baj) + (1.f - alpha) * xv;
    }
    __syncthreads();

    const int wave = j >> 6, lane = j & 63;
    float gam0 = gamma[lane], gam1 = gamma[lane + 64];
    float bet0 = beta[lane],  bet1 = beta[lane + 64];
    for (int r = wave; r < ROWS; r += 2) {
        int row = block_row + r;
        if (row >= N_NODES) break;
        float v0 = hs[r][lane], v1 = hs[r][lane + 64];
        float s = v0 + v1, s2 = v0 * v0 + v1 * v1;
        #pragma unroll
        for (int off = 1; off < 64; off <<= 1) {
            s  += __shfl_xor(s,  off, 64);
            s2 += __shfl_xor(s2, off, 64);
        }
        float mu = s * (1.f / 128.f);
        float var = s2 * (1.f / 128.f) - mu * mu;
        float rstd = rsqrtf(var + LN_EPS);
        out[(size_t)row * DIM + lane]      = (v0 - mu) * rstd * gam0 + bet0;
        out[(size_t)row * DIM + lane + 64] = (v1 - mu) * rstd * gam1 + bet1;
    }
}

extern "C" void kernel_launch(void* const* d_in, const int* in_sizes, int n_in,
                              void* d_out, int out_size, void* d_ws, size_t ws_size,
                              hipStream_t stream) {
    const float* x     = (const float*)d_in[0];
    const int*   src0  = (const int*)d_in[1];
    const int*   dst0  = (const int*)d_in[2];
    const int*   src1  = (const int*)d_in[3];
    const int*   dst1  = (const int*)d_in[4];
    const float* Wk    = (const float*)d_in[5];
    const float* bk    = (const float*)d_in[6];
    const float* Wm    = (const float*)d_in[7];
    const float* bm    = (const float*)d_in[8];
    const float* Wq    = (const float*)d_in[9];
    const float* bq    = (const float*)d_in[10];
    const float* Wa    = (const float*)d_in[11];
    const float* ba    = (const float*)d_in[12];
    const float* Watt0 = (const float*)d_in[13];
    const float* Wmsg0 = (const float*)d_in[14];
    const float* Watt1 = (const float*)d_in[15];
    const float* Wmsg1 = (const float*)d_in[16];
    const float* prior0= (const float*)d_in[17];
    const float* prior1= (const float*)d_in[18];
    const float* skip  = (const float*)d_in[19];
    const float* gamma = (const float*)d_in[20];
    const float* beta  = (const float*)d_in[21];
    float* out = (float*)d_out;

    const size_t nd = (size_t)N_NODES * DIM;
    // Workspace layout (total 208.0 MB — same proven footprint as round 0):
    //   katt0 [nd f32] | katt1 [nd f32] | pooled [nd f32] | denom [N*NH f32]
    //   | mmsg0 [nd bf16] | mmsg1 [nd bf16]
    float* ws = (float*)d_ws;
    float* katt0  = ws;
    float* katt1  = katt0 + nd;
    float* pooled = katt1 + nd;
    float* denomb = pooled + nd;
    __hip_bfloat16* mmsg0 = (__hip_bfloat16*)(denomb + (size_t)N_NODES * NH);
    __hip_bfloat16* mmsg1 = mmsg0 + nd;
    // q lives in d_out (dead before final_kernel writes the real output)
    float* qbuf = out;

    // zero accumulators (pooled + denom are contiguous)
    hipMemsetAsync(pooled, 0, (nd + (size_t)N_NODES * NH) * sizeof(float), stream);

    dim3 blk(128), grd((N_NODES + 15) / 16);
    proj_kernel<<<grd, blk, 0, stream>>>(
        x, Wk, bk, Wm, bm, Wq, bq,
        Watt0, Wmsg0, Watt1, Wmsg1, prior0, prior1,
        qbuf, katt0, katt1, mmsg0, mmsg1);
    edge_kernel<<<dim3(16384), dim3(256), 0, stream>>>(
        katt0, katt1, mmsg0, mmsg1, qbuf,
        src0, dst0, src1, dst1, pooled, denomb);
    final_kernel<<<grd, blk, 0, stream>>>(pooled, denomb, x, Wa, ba, skip, gamma, beta, out);
}

// Round 4
// 601.228 us; speedup vs baseline: 1.7023x; 1.5132x over previous
//
#include <hip/hip_runtime.h>
#include <hip/hip_bf16.h>
#include <math.h>

#define N_NODES 100000
#define DIM 128
#define NH 8
#define NC 16
#define E_EDGES 400000
#define LN_EPS 1e-3f
#define SCAN_B 1024

// ---------------- Kernel 1: fused k/m/q projections + relation projections ----
// Outputs: q (N,128 fp32, in d_out), kattC (2N,128 bf16: rows [0,N)=set0
// scaled by prior0/sqrt(C), rows [N,2N)=set1), mmsgC (2N,128 bf16).
__global__ __launch_bounds__(128) void proj_kernel(
    const float* __restrict__ x,
    const float* __restrict__ Wk, const float* __restrict__ bk,
    const float* __restrict__ Wm, const float* __restrict__ bm,
    const float* __restrict__ Wq, const float* __restrict__ bq,
    const float* __restrict__ Watt0, const float* __restrict__ Wmsg0,
    const float* __restrict__ Watt1, const float* __restrict__ Wmsg1,
    const float* __restrict__ prior0, const float* __restrict__ prior1,
    float* __restrict__ qout,
    __hip_bfloat16* __restrict__ kattC, __hip_bfloat16* __restrict__ mmsgC)
{
    const int ROWS = 16;
    __shared__ float xs[ROWS][DIM];
    __shared__ float ks[ROWS][DIM];
    __shared__ float ms[ROWS][DIM];
    const int block_row = blockIdx.x * ROWS;
    const int j = threadIdx.x;
    const int h = j >> 4, l = j & 15;

    #pragma unroll
    for (int r = 0; r < ROWS; ++r) {
        int row = block_row + r;
        xs[r][j] = (row < N_NODES) ? x[(size_t)row * DIM + j] : 0.f;
    }
    __syncthreads();

    float acck[ROWS], accm[ROWS], accq[ROWS];
    #pragma unroll
    for (int r = 0; r < ROWS; ++r) { acck[r] = 0.f; accm[r] = 0.f; accq[r] = 0.f; }

    for (int d = 0; d < DIM; ++d) {
        float wk = Wk[d * DIM + j];
        float wm = Wm[d * DIM + j];
        float wq = Wq[d * DIM + j];
        #pragma unroll
        for (int r = 0; r < ROWS; ++r) {
            float xv = xs[r][d];
            acck[r] = fmaf(xv, wk, acck[r]);
            accm[r] = fmaf(xv, wm, accm[r]);
            accq[r] = fmaf(xv, wq, accq[r]);
        }
    }

    const float bkj = bk[j], bmj = bm[j], bqj = bq[j];
    #pragma unroll
    for (int r = 0; r < ROWS; ++r) {
        int row = block_row + r;
        if (row < N_NODES) qout[(size_t)row * DIM + j] = accq[r] + bqj;
        ks[r][j] = acck[r] + bkj;
        ms[r][j] = accm[r] + bmj;
    }
    __syncthreads();

    // Per-head 16x16 relation projections, outputs cast to bf16.
    const float sc = 0.25f;  // 1/sqrt(16)
    {
        float w[NC];
        #pragma unroll
        for (int kk = 0; kk < NC; ++kk) w[kk] = Watt0[(h * NC + kk) * NC + l];
        float p = prior0[h] * sc;
        #pragma unroll
        for (int r = 0; r < ROWS; ++r) {
            int row = block_row + r;
            if (row >= N_NODES) break;
            float s = 0.f;
            #pragma unroll
            for (int kk = 0; kk < NC; ++kk) s = fmaf(ks[r][h * NC + kk], w[kk], s);
            kattC[(size_t)row * DIM + j] = __float2bfloat16(s * p);
        }
    }
    {
        float w[NC];
        #pragma unroll
        for (int kk = 0; kk < NC; ++kk) w[kk] = Watt1[(h * NC + kk) * NC + l];
        float p = prior1[h] * sc;
        #pragma unroll
        for (int r = 0; r < ROWS; ++r) {
            int row = block_row + r;
            if (row >= N_NODES) break;
            float s = 0.f;
            #pragma unroll
            for (int kk = 0; kk < NC; ++kk) s = fmaf(ks[r][h * NC + kk], w[kk], s);
            kattC[((size_t)N_NODES + row) * DIM + j] = __float2bfloat16(s * p);
        }
    }
    {
        float w[NC];
        #pragma unroll
        for (int kk = 0; kk < NC; ++kk) w[kk] = Wmsg0[(h * NC + kk) * NC + l];
        #pragma unroll
        for (int r = 0; r < ROWS; ++r) {
            int row = block_row + r;
            if (row >= N_NODES) break;
            float s = 0.f;
            #pragma unroll
            for (int kk = 0; kk < NC; ++kk) s = fmaf(ms[r][h * NC + kk], w[kk], s);
            mmsgC[(size_t)row * DIM + j] = __float2bfloat16(s);
        }
    }
    {
        float w[NC];
        #pragma unroll
        for (int kk = 0; kk < NC; ++kk) w[kk] = Wmsg1[(h * NC + kk) * NC + l];
        #pragma unroll
        for (int r = 0; r < ROWS; ++r) {
            int row = block_row + r;
            if (row >= N_NODES) break;
            float s = 0.f;
            #pragma unroll
            for (int kk = 0; kk < NC; ++kk) s = fmaf(ms[r][h * NC + kk], w[kk], s);
            mmsgC[((size_t)N_NODES + row) * DIM + j] = __float2bfloat16(s);
        }
    }
}

// ---------------- CSR build ----------------
__global__ __launch_bounds__(256) void hist_kernel(
    const int* __restrict__ dst0, const int* __restrict__ dst1,
    int* __restrict__ counts)
{
    int e = blockIdx.x * 256 + threadIdx.x;
    if (e < E_EDGES) atomicAdd(&counts[dst0[e]], 1);
    int e1 = e - E_EDGES;
    if (e1 >= 0 && e1 < E_EDGES) atomicAdd(&counts[dst1[e1]], 1);
}

__global__ __launch_bounds__(SCAN_B) void scanA_kernel(
    const int* __restrict__ counts, int* __restrict__ row_ptr,
    int* __restrict__ bsum)
{
    __shared__ int buf[2][SCAN_B];
    int i = blockIdx.x * SCAN_B + threadIdx.x;
    int v = (i < N_NODES) ? counts[i] : 0;
    int cur = 0;
    buf[0][threadIdx.x] = v;
    __syncthreads();
    #pragma unroll
    for (int off = 1; off < SCAN_B; off <<= 1) {
        int t = buf[cur][threadIdx.x];
        int add = (threadIdx.x >= off) ? buf[cur][threadIdx.x - off] : 0;
        buf[cur ^ 1][threadIdx.x] = t + add;
        cur ^= 1;
        __syncthreads();
    }
    int inc = buf[cur][threadIdx.x];
    if (i < N_NODES) row_ptr[i] = inc - v;           // exclusive within block
    if (threadIdx.x == SCAN_B - 1) bsum[blockIdx.x] = inc;
}

__global__ void scanB_kernel(int* __restrict__ bsum, int nblocks)
{
    if (threadIdx.x == 0 && blockIdx.x == 0) {
        int running = 0;
        for (int b = 0; b < nblocks; ++b) {
            int t = bsum[b]; bsum[b] = running; running += t;
        }
    }
}

__global__ __launch_bounds__(SCAN_B) void scanC_kernel(
    int* __restrict__ row_ptr, int* __restrict__ cursor,
    const int* __restrict__ bsum)
{
    int i = blockIdx.x * SCAN_B + threadIdx.x;
    if (i < N_NODES) {
        int r = row_ptr[i] + bsum[blockIdx.x];
        row_ptr[i] = r;
        cursor[i] = r;
    }
}

__global__ __launch_bounds__(256) void scatter_kernel(
    const int* __restrict__ src0, const int* __restrict__ dst0,
    const int* __restrict__ src1, const int* __restrict__ dst1,
    int* __restrict__ cursor, unsigned int* __restrict__ eidx)
{
    int e = blockIdx.x * 256 + threadIdx.x;
    if (e < E_EDGES) {
        int d = dst0[e];
        int pos = atomicAdd(&cursor[d], 1);
        eidx[pos] = (unsigned int)src0[e];
    }
    int e1 = e - E_EDGES;
    if (e1 >= 0 && e1 < E_EDGES) {
        int d = dst1[e1];
        int pos = atomicAdd(&cursor[d], 1);
        eidx[pos] = (unsigned int)(src1[e1] + N_NODES);
    }
}

// ---------------- Kernel 2: dst-owned aggregation (one wave per node) --------
// Lane owns channel pair (2*lane, 2*lane+1) — both in head lane>>3.
// Writes pooled = gelu( sum(es*msg)/sum(es) ) once per node. No atomics.
__global__ __launch_bounds__(256) void agg_kernel(
    const __hip_bfloat162* __restrict__ katt,   // [2N][64] channel pairs
    const __hip_bfloat162* __restrict__ mmsg,   // [2N][64]
    const float2* __restrict__ q2,              // [N][64]
    const int* __restrict__ row_ptr, const int* __restrict__ counts,
    const unsigned int* __restrict__ eidx,
    float2* __restrict__ pooled2)               // [N][64]
{
    const int wave = threadIdx.x >> 6, lane = threadIdx.x & 63;
    const int n = blockIdx.x * 4 + wave;
    if (n >= N_NODES) return;
    const int start = row_ptr[n], cnt = counts[n];
    const float2 qq = q2[(size_t)n * 64 + lane];

    float accx = 0.f, accy = 0.f, den = 0.f;
    int i = 0;
    for (; i + 2 <= cnt; i += 2) {
        unsigned int r0 = eidx[start + i];
        unsigned int r1 = eidx[start + i + 1];
        __hip_bfloat162 ka0 = katt[(size_t)r0 * 64 + lane];
        __hip_bfloat162 ka1 = katt[(size_t)r1 * 64 + lane];
        __hip_bfloat162 mg0 = mmsg[(size_t)r0 * 64 + lane];
        __hip_bfloat162 mg1 = mmsg[(size_t)r1 * 64 + lane];
        float p0 = fmaf(__bfloat162float(ka0.x), qq.x,
                        __bfloat162float(ka0.y) * qq.y);
        float p1 = fmaf(__bfloat162float(ka1.x), qq.x,
                        __bfloat162float(ka1.y) * qq.y);
        p0 += __shfl_xor(p0, 1, 64); p0 += __shfl_xor(p0, 2, 64); p0 += __shfl_xor(p0, 4, 64);
        p1 += __shfl_xor(p1, 1, 64); p1 += __shfl_xor(p1, 2, 64); p1 += __shfl_xor(p1, 4, 64);
        float e0 = expf(p0), e1 = expf(p1);
        accx = fmaf(e0, __bfloat162float(mg0.x), accx);
        accy = fmaf(e0, __bfloat162float(mg0.y), accy);
        accx = fmaf(e1, __bfloat162float(mg1.x), accx);
        accy = fmaf(e1, __bfloat162float(mg1.y), accy);
        den += e0 + e1;
    }
    if (i < cnt) {
        unsigned int r0 = eidx[start + i];
        __hip_bfloat162 ka0 = katt[(size_t)r0 * 64 + lane];
        __hip_bfloat162 mg0 = mmsg[(size_t)r0 * 64 + lane];
        float p0 = fmaf(__bfloat162float(ka0.x), qq.x,
                        __bfloat162float(ka0.y) * qq.y);
        p0 += __shfl_xor(p0, 1, 64); p0 += __shfl_xor(p0, 2, 64); p0 += __shfl_xor(p0, 4, 64);
        float e0 = expf(p0);
        accx = fmaf(e0, __bfloat162float(mg0.x), accx);
        accy = fmaf(e0, __bfloat162float(mg0.y), accy);
        den += e0;
    }

    float vx = 0.f, vy = 0.f;
    if (den > 0.f) { vx = accx / den; vy = accy / den; }
    vx = 0.5f * vx * (1.f + erff(vx * 0.70710678118654752f));
    vy = 0.5f * vy * (1.f + erff(vy * 0.70710678118654752f));
    pooled2[(size_t)n * 64 + lane] = make_float2(vx, vy);
}

// ---------------- Kernel 3: GEMM(Wa) -> skip -> LayerNorm (gelu pre-applied) --
__global__ __launch_bounds__(128) void final_kernel(
    const float* __restrict__ pooled,
    const float* __restrict__ x,
    const float* __restrict__ Wa, const float* __restrict__ ba,
    const float* __restrict__ skip, const float* __restrict__ gamma,
    const float* __restrict__ beta,
    float* __restrict__ out)
{
    const int ROWS = 16;
    __shared__ float gs[ROWS][DIM];
    __shared__ float hs[ROWS][DIM];
    const int block_row = blockIdx.x * ROWS;
    const int j = threadIdx.x;

    #pragma unroll
    for (int r = 0; r < ROWS; ++r) {
        int row = block_row + r;
        gs[r][j] = (row < N_NODES) ? pooled[(size_t)row * DIM + j] : 0.f;
    }
    __syncthreads();

    float acc[ROWS];
    #pragma unroll
    for (int r = 0; r < ROWS; ++r) acc[r] = 0.f;
    for (int d = 0; d < DIM; ++d) {
        float w = Wa[d * DIM + j];
        #pragma unroll
        for (int r = 0; r < ROWS; ++r) acc[r] = fmaf(gs[r][d], w, acc[r]);
    }

    float alpha = 1.f / (1.f + expf(-skip[0]));
    float baj = ba[j];
    #pragma unroll
    for (int r = 0; r < ROWS; ++r) {
        int row = block_row + r;
        float xv = (row < N_NODES) ? x[(size_t)row * DIM + j] : 0.f;
        hs[r][j] = alpha * (acc[r] + baj) + (1.f - alpha) * xv;
    }
    __syncthreads();

    const int wave = j >> 6, lane = j & 63;
    float gam0 = gamma[lane], gam1 = gamma[lane + 64];
    float bet0 = beta[lane],  bet1 = beta[lane + 64];
    for (int r = wave; r < ROWS; r += 2) {
        int row = block_row + r;
        if (row >= N_NODES) break;
        float v0 = hs[r][lane], v1 = hs[r][lane + 64];
        float s = v0 + v1, s2 = v0 * v0 + v1 * v1;
        #pragma unroll
        for (int off = 1; off < 64; off <<= 1) {
            s  += __shfl_xor(s,  off, 64);
            s2 += __shfl_xor(s2, off, 64);
        }
        float mu = s * (1.f / 128.f);
        float var = s2 * (1.f / 128.f) - mu * mu;
        float rstd = rsqrtf(var + LN_EPS);
        out[(size_t)row * DIM + lane]      = (v0 - mu) * rstd * gam0 + bet0;
        out[(size_t)row * DIM + lane + 64] = (v1 - mu) * rstd * gam1 + bet1;
    }
}

extern "C" void kernel_launch(void* const* d_in, const int* in_sizes, int n_in,
                              void* d_out, int out_size, void* d_ws, size_t ws_size,
                              hipStream_t stream) {
    const float* x     = (const float*)d_in[0];
    const int*   src0  = (const int*)d_in[1];
    const int*   dst0  = (const int*)d_in[2];
    const int*   src1  = (const int*)d_in[3];
    const int*   dst1  = (const int*)d_in[4];
    const float* Wk    = (const float*)d_in[5];
    const float* bk    = (const float*)d_in[6];
    const float* Wm    = (const float*)d_in[7];
    const float* bm    = (const float*)d_in[8];
    const float* Wq    = (const float*)d_in[9];
    const float* bq    = (const float*)d_in[10];
    const float* Wa    = (const float*)d_in[11];
    const float* ba    = (const float*)d_in[12];
    const float* Watt0 = (const float*)d_in[13];
    const float* Wmsg0 = (const float*)d_in[14];
    const float* Watt1 = (const float*)d_in[15];
    const float* Wmsg1 = (const float*)d_in[16];
    const float* prior0= (const float*)d_in[17];
    const float* prior1= (const float*)d_in[18];
    const float* skip  = (const float*)d_in[19];
    const float* gamma = (const float*)d_in[20];
    const float* beta  = (const float*)d_in[21];
    float* out = (float*)d_out;

    const size_t nd = (size_t)N_NODES * DIM;
    // Workspace layout (~158 MB):
    //   pooled [nd f32] | kattC [2*nd bf16] | mmsgC [2*nd bf16]
    //   | counts [N i32] | row_ptr [N i32] | cursor [N i32] | bsum [128 i32]
    //   | eidx [2E u32]
    char* wsb = (char*)d_ws;
    float* pooled = (float*)wsb;                         wsb += nd * 4;
    __hip_bfloat16* kattC = (__hip_bfloat16*)wsb;        wsb += 2 * nd * 2;
    __hip_bfloat16* mmsgC = (__hip_bfloat16*)wsb;        wsb += 2 * nd * 2;
    int* counts  = (int*)wsb;                            wsb += (size_t)N_NODES * 4;
    int* row_ptr = (int*)wsb;                            wsb += (size_t)N_NODES * 4;
    int* cursor  = (int*)wsb;                            wsb += (size_t)N_NODES * 4;
    int* bsum    = (int*)wsb;                            wsb += 128 * 4;
    unsigned int* eidx = (unsigned int*)wsb;
    // q lives in d_out (dead before final_kernel writes the real output)
    float* qbuf = out;

    hipMemsetAsync(counts, 0, (size_t)N_NODES * 4, stream);

    const int scan_blocks = (N_NODES + SCAN_B - 1) / SCAN_B;   // 98
    const int edge_blocks = (2 * E_EDGES + 255) / 256;         // 3125

    hist_kernel<<<dim3(edge_blocks), dim3(256), 0, stream>>>(dst0, dst1, counts);
    scanA_kernel<<<dim3(scan_blocks), dim3(SCAN_B), 0, stream>>>(counts, row_ptr, bsum);
    scanB_kernel<<<dim3(1), dim3(64), 0, stream>>>(bsum, scan_blocks);
    scanC_kernel<<<dim3(scan_blocks), dim3(SCAN_B), 0, stream>>>(row_ptr, cursor, bsum);
    scatter_kernel<<<dim3(edge_blocks), dim3(256), 0, stream>>>(
        src0, dst0, src1, dst1, cursor, eidx);

    dim3 blk(128), grd((N_NODES + 15) / 16);
    proj_kernel<<<grd, blk, 0, stream>>>(
        x, Wk, bk, Wm, bm, Wq, bq,
        Watt0, Wmsg0, Watt1, Wmsg1, prior0, prior1,
        qbuf, kattC, mmsgC);

    agg_kernel<<<dim3((N_NODES + 3) / 4), dim3(256), 0, stream>>>(
        (const __hip_bfloat162*)kattC, (const __hip_bfloat162*)mmsgC,
        (const float2*)qbuf, row_ptr, counts, eidx, (float2*)pooled);

    final_kernel<<<grd, blk, 0, stream>>>(pooled, x, Wa, ba, skip, gamma, beta, out);
}

// Round 5
// 430.921 us; speedup vs baseline: 2.3750x; 1.3952x over previous
//
#include <hip/hip_runtime.h>
#include <hip/hip_bf16.h>
#include <math.h>

#define N_NODES 100000
#define DIM 128
#define NH 8
#define NC 16
#define E_EDGES 400000
#define LN_EPS 1e-3f
#define SCAN_B 1024

typedef __attribute__((ext_vector_type(8))) short short8v;
typedef __attribute__((ext_vector_type(4))) float float4v;

// ---------------- x -> bf16 cast ----------------
__global__ __launch_bounds__(256) void xcast_kernel(
    const float4* __restrict__ x4, __hip_bfloat162* __restrict__ xb2)
{
    int i = blockIdx.x * 256 + threadIdx.x;   // one float4 per thread
    if (i < (N_NODES * DIM) / 4) {
        float4 v = x4[i];
        __hip_bfloat162 a, b;
        a.x = __float2bfloat16(v.x); a.y = __float2bfloat16(v.y);
        b.x = __float2bfloat16(v.z); b.y = __float2bfloat16(v.w);
        xb2[2 * i] = a;
        xb2[2 * i + 1] = b;
    }
}

// ---------------- fused transposed weights (bf16) + fused biases -------------
// Wt[c][d], c in [0,768): sections of 128 cols:
//  0: Wk·BD(Watt0)·prior0/sqrt(C)   1: Wk·BD(Watt1)·prior1/sqrt(C)
//  2: Wm·BD(Wmsg0)                  3: Wm·BD(Wmsg1)
//  4: Wq                            5: Wa
// bias[c] similarly fused (bk/bm pushed through the relation weights).
__global__ __launch_bounds__(128) void fuse_weights(
    const float* __restrict__ Wk, const float* __restrict__ bk,
    const float* __restrict__ Wm, const float* __restrict__ bm,
    const float* __restrict__ Wq, const float* __restrict__ bq,
    const float* __restrict__ Wa, const float* __restrict__ ba,
    const float* __restrict__ Watt0, const float* __restrict__ Wmsg0,
    const float* __restrict__ Watt1, const float* __restrict__ Wmsg1,
    const float* __restrict__ prior0, const float* __restrict__ prior1,
    __hip_bfloat16* __restrict__ Wt, float* __restrict__ bias)
{
    const int c = blockIdx.x;        // 0..767
    const int d = threadIdx.x;       // 0..127
    const int sec = c >> 7, j = c & 127, h = j >> 4, l = j & 15;
    float v, b;
    if (sec == 4)      { v = Wq[d * DIM + j]; b = bq[j]; }
    else if (sec == 5) { v = Wa[d * DIM + j]; b = ba[j]; }
    else {
        const float* W1 = (sec < 2) ? Wk : Wm;
        const float* bs = (sec < 2) ? bk : bm;
        const float* W2 = (sec == 0) ? Watt0 : (sec == 1) ? Watt1
                          : (sec == 2) ? Wmsg0 : Wmsg1;
        float scale = (sec == 0) ? prior0[h] * 0.25f
                    : (sec == 1) ? prior1[h] * 0.25f : 1.f;
        float s = 0.f, sb = 0.f;
        #pragma unroll
        for (int kk = 0; kk < NC; ++kk) {
            float w2 = W2[h * 256 + kk * 16 + l];
            s  = fmaf(W1[d * DIM + h * 16 + kk], w2, s);
            sb = fmaf(bs[h * 16 + kk], w2, sb);
        }
        v = s * scale; b = sb * scale;
    }
    Wt[(size_t)c * DIM + d] = __float2bfloat16(v);
    if (d == 0) bias[c] = b;
}

// ---------------- proj: one bf16 MFMA GEMM [N,128]@[128,640] -----------------
// Block = 256 threads (4 waves), 32 rows. Wave w owns cols [w*160, w*160+160).
// Outputs: katt0/katt1 -> kattC[2N][128] bf16, mmsg -> mmsgC, q -> fp32.
__global__ __launch_bounds__(256) void proj_mfma(
    const __hip_bfloat16* __restrict__ xb,   // [N][128]
    const __hip_bfloat16* __restrict__ Wt,   // [768][128]
    const float* __restrict__ bias,          // [768]
    __hip_bfloat16* __restrict__ kattC,      // [2N][128]
    __hip_bfloat16* __restrict__ mmsgC,      // [2N][128]
    float* __restrict__ qout)                // [N][128]
{
    const int wave = threadIdx.x >> 6, lane = threadIdx.x & 63;
    const int quad = lane >> 4, mcol = lane & 15;
    const int r0 = blockIdx.x * 32;

    short8v a0[4], a1[4];
    const short* xp0 = (const short*)xb + (size_t)(r0 + mcol) * DIM + quad * 8;
    const short* xp1 = xp0 + 16 * DIM;
    #pragma unroll
    for (int kb = 0; kb < 4; ++kb) {
        a0[kb] = *(const short8v*)(xp0 + kb * 32);
        a1[kb] = *(const short8v*)(xp1 + kb * 32);
    }

    #pragma unroll
    for (int t = 0; t < 10; ++t) {
        const int c0 = wave * 160 + t * 16;
        const short* wp = (const short*)Wt + (size_t)(c0 + mcol) * DIM + quad * 8;
        float4v acc0 = {0.f, 0.f, 0.f, 0.f};
        float4v acc1 = {0.f, 0.f, 0.f, 0.f};
        #pragma unroll
        for (int kb = 0; kb < 4; ++kb) {
            short8v bfr = *(const short8v*)(wp + kb * 32);
            acc0 = __builtin_amdgcn_mfma_f32_16x16x32_bf16(a0[kb], bfr, acc0, 0, 0, 0);
            acc1 = __builtin_amdgcn_mfma_f32_16x16x32_bf16(a1[kb], bfr, acc1, 0, 0, 0);
        }
        const float bcol = bias[c0 + mcol];
        const int sec = c0 >> 7;
        const int cc = (c0 & 127) + mcol;
        const int rb0 = r0 + quad * 4;
        if (sec == 4) {
            #pragma unroll
            for (int g = 0; g < 4; ++g) {
                qout[(size_t)(rb0 + g) * DIM + cc]      = acc0[g] + bcol;
                qout[(size_t)(rb0 + 16 + g) * DIM + cc] = acc1[g] + bcol;
            }
        } else {
            __hip_bfloat16* dst = (sec < 2) ? kattC : mmsgC;
            const size_t off = (sec & 1) ? (size_t)N_NODES * DIM : 0;
            #pragma unroll
            for (int g = 0; g < 4; ++g) {
                dst[off + (size_t)(rb0 + g) * DIM + cc]      = __float2bfloat16(acc0[g] + bcol);
                dst[off + (size_t)(rb0 + 16 + g) * DIM + cc] = __float2bfloat16(acc1[g] + bcol);
            }
        }
    }
}

// ---------------- CSR build ----------------
__global__ __launch_bounds__(256) void hist_kernel(
    const int* __restrict__ dst0, const int* __restrict__ dst1,
    int* __restrict__ counts)
{
    int e = blockIdx.x * 256 + threadIdx.x;
    if (e < E_EDGES) atomicAdd(&counts[dst0[e]], 1);
    int e1 = e - E_EDGES;
    if (e1 >= 0 && e1 < E_EDGES) atomicAdd(&counts[dst1[e1]], 1);
}

__global__ __launch_bounds__(SCAN_B) void scanA_kernel(
    const int* __restrict__ counts, int* __restrict__ row_ptr,
    int* __restrict__ bsum)
{
    __shared__ int buf[2][SCAN_B];
    int i = blockIdx.x * SCAN_B + threadIdx.x;
    int v = (i < N_NODES) ? counts[i] : 0;
    int cur = 0;
    buf[0][threadIdx.x] = v;
    __syncthreads();
    #pragma unroll
    for (int off = 1; off < SCAN_B; off <<= 1) {
        int t = buf[cur][threadIdx.x];
        int add = (threadIdx.x >= off) ? buf[cur][threadIdx.x - off] : 0;
        buf[cur ^ 1][threadIdx.x] = t + add;
        cur ^= 1;
        __syncthreads();
    }
    int inc = buf[cur][threadIdx.x];
    if (i < N_NODES) row_ptr[i] = inc - v;
    if (threadIdx.x == SCAN_B - 1) bsum[blockIdx.x] = inc;
}

__global__ void scanB_kernel(int* __restrict__ bsum, int nblocks)
{
    if (threadIdx.x == 0 && blockIdx.x == 0) {
        int running = 0;
        for (int b = 0; b < nblocks; ++b) {
            int t = bsum[b]; bsum[b] = running; running += t;
        }
    }
}

__global__ __launch_bounds__(SCAN_B) void scanC_kernel(
    int* __restrict__ row_ptr, int* __restrict__ cursor,
    const int* __restrict__ bsum)
{
    int i = blockIdx.x * SCAN_B + threadIdx.x;
    if (i < N_NODES) {
        int r = row_ptr[i] + bsum[blockIdx.x];
        row_ptr[i] = r;
        cursor[i] = r;
    }
}

__global__ __launch_bounds__(256) void scatter_kernel(
    const int* __restrict__ src0, const int* __restrict__ dst0,
    const int* __restrict__ src1, const int* __restrict__ dst1,
    int* __restrict__ cursor, unsigned int* __restrict__ eidx)
{
    int e = blockIdx.x * 256 + threadIdx.x;
    if (e < E_EDGES) {
        int d = dst0[e];
        int pos = atomicAdd(&cursor[d], 1);
        eidx[pos] = (unsigned int)src0[e];
    }
    int e1 = e - E_EDGES;
    if (e1 >= 0 && e1 < E_EDGES) {
        int d = dst1[e1];
        int pos = atomicAdd(&cursor[d], 1);
        eidx[pos] = (unsigned int)(src1[e1] + N_NODES);
    }
}

// ---------------- aggregation: one wave per node, no atomics -----------------
// Lane owns channel pair (2*lane, 2*lane+1). Writes gelu(pooled/denom) in bf16.
__global__ __launch_bounds__(256) void agg_kernel(
    const __hip_bfloat162* __restrict__ katt,   // [2N][64] channel pairs
    const __hip_bfloat162* __restrict__ mmsg,   // [2N][64]
    const float2* __restrict__ q2,              // [N][64]
    const int* __restrict__ row_ptr, const int* __restrict__ counts,
    const unsigned int* __restrict__ eidx,
    __hip_bfloat162* __restrict__ pooled2)      // [N][64]
{
    const int wave = threadIdx.x >> 6, lane = threadIdx.x & 63;
    const int n = blockIdx.x * 4 + wave;
    if (n >= N_NODES) return;
    const int start = row_ptr[n], cnt = counts[n];
    const float2 qq = q2[(size_t)n * 64 + lane];

    float accx = 0.f, accy = 0.f, den = 0.f;
    int i = 0;
    for (; i + 2 <= cnt; i += 2) {
        unsigned int r0 = eidx[start + i];
        unsigned int r1 = eidx[start + i + 1];
        __hip_bfloat162 ka0 = katt[(size_t)r0 * 64 + lane];
        __hip_bfloat162 ka1 = katt[(size_t)r1 * 64 + lane];
        __hip_bfloat162 mg0 = mmsg[(size_t)r0 * 64 + lane];
        __hip_bfloat162 mg1 = mmsg[(size_t)r1 * 64 + lane];
        float p0 = fmaf(__bfloat162float(ka0.x), qq.x,
                        __bfloat162float(ka0.y) * qq.y);
        float p1 = fmaf(__bfloat162float(ka1.x), qq.x,
                        __bfloat162float(ka1.y) * qq.y);
        p0 += __shfl_xor(p0, 1, 64); p0 += __shfl_xor(p0, 2, 64); p0 += __shfl_xor(p0, 4, 64);
        p1 += __shfl_xor(p1, 1, 64); p1 += __shfl_xor(p1, 2, 64); p1 += __shfl_xor(p1, 4, 64);
        float e0 = expf(p0), e1 = expf(p1);
        accx = fmaf(e0, __bfloat162float(mg0.x), accx);
        accy = fmaf(e0, __bfloat162float(mg0.y), accy);
        accx = fmaf(e1, __bfloat162float(mg1.x), accx);
        accy = fmaf(e1, __bfloat162float(mg1.y), accy);
        den += e0 + e1;
    }
    if (i < cnt) {
        unsigned int r0 = eidx[start + i];
        __hip_bfloat162 ka0 = katt[(size_t)r0 * 64 + lane];
        __hip_bfloat162 mg0 = mmsg[(size_t)r0 * 64 + lane];
        float p0 = fmaf(__bfloat162float(ka0.x), qq.x,
                        __bfloat162float(ka0.y) * qq.y);
        p0 += __shfl_xor(p0, 1, 64); p0 += __shfl_xor(p0, 2, 64); p0 += __shfl_xor(p0, 4, 64);
        float e0 = expf(p0);
        accx = fmaf(e0, __bfloat162float(mg0.x), accx);
        accy = fmaf(e0, __bfloat162float(mg0.y), accy);
        den += e0;
    }

    float vx = 0.f, vy = 0.f;
    if (den > 0.f) { vx = accx / den; vy = accy / den; }
    vx = 0.5f * vx * (1.f + erff(vx * 0.70710678118654752f));
    vy = 0.5f * vy * (1.f + erff(vy * 0.70710678118654752f));
    __hip_bfloat162 o; o.x = __float2bfloat16(vx); o.y = __float2bfloat16(vy);
    pooled2[(size_t)n * 64 + lane] = o;
}

// ---------------- final: MFMA GEMM(Wa) -> skip -> LayerNorm ------------------
// Block = 256 threads (4 waves), 32 rows. Wave w owns cols [w*32, w*32+32).
__global__ __launch_bounds__(256) void final_mfma(
    const __hip_bfloat16* __restrict__ pooled,  // [N][128] bf16, gelu applied
    const __hip_bfloat16* __restrict__ Wt,      // [768][128]; rows 640.. = Wa^T
    const float* __restrict__ bias,             // [768]; 640.. = ba
    const float* __restrict__ x,
    const float* __restrict__ skip, const float* __restrict__ gamma,
    const float* __restrict__ beta, float* __restrict__ out)
{
    __shared__ float hs[32][DIM];
    const int wave = threadIdx.x >> 6, lane = threadIdx.x & 63;
    const int quad = lane >> 4, mcol = lane & 15;
    const int r0 = blockIdx.x * 32;

    short8v a0[4], a1[4];
    const short* pp0 = (const short*)pooled + (size_t)(r0 + mcol) * DIM + quad * 8;
    const short* pp1 = pp0 + 16 * DIM;
    #pragma unroll
    for (int kb = 0; kb < 4; ++kb) {
        a0[kb] = *(const short8v*)(pp0 + kb * 32);
        a1[kb] = *(const short8v*)(pp1 + kb * 32);
    }
    const float alpha = 1.f / (1.f + expf(-skip[0]));

    #pragma unroll
    for (int t = 0; t < 2; ++t) {
        const int c0 = wave * 32 + t * 16;
        const short* wp = (const short*)Wt + (size_t)(640 + c0 + mcol) * DIM + quad * 8;
        float4v acc0 = {0.f, 0.f, 0.f, 0.f};
        float4v acc1 = {0.f, 0.f, 0.f, 0.f};
        #pragma unroll
        for (int kb = 0; kb < 4; ++kb) {
            short8v bfr = *(const short8v*)(wp + kb * 32);
            acc0 = __builtin_amdgcn_mfma_f32_16x16x32_bf16(a0[kb], bfr, acc0, 0, 0, 0);
            acc1 = __builtin_amdgcn_mfma_f32_16x16x32_bf16(a1[kb], bfr, acc1, 0, 0, 0);
        }
        const float bcol = bias[640 + c0 + mcol];
        const int cc = c0 + mcol;
        const int rq = quad * 4;
        #pragma unroll
        for (int g = 0; g < 4; ++g) {
            int rA = rq + g, rB = rq + 16 + g;
            hs[rA][cc] = alpha * (acc0[g] + bcol)
                       + (1.f - alpha) * x[(size_t)(r0 + rA) * DIM + cc];
            hs[rB][cc] = alpha * (acc1[g] + bcol)
                       + (1.f - alpha) * x[(size_t)(r0 + rB) * DIM + cc];
        }
    }
    __syncthreads();

    float gam0 = gamma[lane], gam1 = gamma[lane + 64];
    float bet0 = beta[lane],  bet1 = beta[lane + 64];
    for (int r = wave; r < 32; r += 4) {
        int row = r0 + r;
        float v0 = hs[r][lane], v1 = hs[r][lane + 64];
        float s = v0 + v1, s2 = v0 * v0 + v1 * v1;
        #pragma unroll
        for (int off = 1; off < 64; off <<= 1) {
            s  += __shfl_xor(s,  off, 64);
            s2 += __shfl_xor(s2, off, 64);
        }
        float mu = s * (1.f / 128.f);
        float var = s2 * (1.f / 128.f) - mu * mu;
        float rstd = rsqrtf(var + LN_EPS);
        out[(size_t)row * DIM + lane]      = (v0 - mu) * rstd * gam0 + bet0;
        out[(size_t)row * DIM + lane + 64] = (v1 - mu) * rstd * gam1 + bet1;
    }
}

extern "C" void kernel_launch(void* const* d_in, const int* in_sizes, int n_in,
                              void* d_out, int out_size, void* d_ws, size_t ws_size,
                              hipStream_t stream) {
    const float* x     = (const float*)d_in[0];
    const int*   src0  = (const int*)d_in[1];
    const int*   dst0  = (const int*)d_in[2];
    const int*   src1  = (const int*)d_in[3];
    const int*   dst1  = (const int*)d_in[4];
    const float* Wk    = (const float*)d_in[5];
    const float* bk    = (const float*)d_in[6];
    const float* Wm    = (const float*)d_in[7];
    const float* bm    = (const float*)d_in[8];
    const float* Wq    = (const float*)d_in[9];
    const float* bq    = (const float*)d_in[10];
    const float* Wa    = (const float*)d_in[11];
    const float* ba    = (const float*)d_in[12];
    const float* Watt0 = (const float*)d_in[13];
    const float* Wmsg0 = (const float*)d_in[14];
    const float* Watt1 = (const float*)d_in[15];
    const float* Wmsg1 = (const float*)d_in[16];
    const float* prior0= (const float*)d_in[17];
    const float* prior1= (const float*)d_in[18];
    const float* skip  = (const float*)d_in[19];
    const float* gamma = (const float*)d_in[20];
    const float* beta  = (const float*)d_in[21];
    float* out = (float*)d_out;

    const size_t nd = (size_t)N_NODES * DIM;
    // Workspace (~158 MB):
    //   x_bf16 [nd bf16] | Wt [768*128 bf16] | bias [768 f32]
    //   | kattC [2nd bf16] | mmsgC [2nd bf16] | pooled [nd bf16]
    //   | counts/row_ptr/cursor [N i32] | bsum [128 i32] | eidx [2E u32]
    char* wsb = (char*)d_ws;
    __hip_bfloat16* xb    = (__hip_bfloat16*)wsb;  wsb += nd * 2;
    __hip_bfloat16* Wt    = (__hip_bfloat16*)wsb;  wsb += (size_t)768 * DIM * 2;
    float* bias           = (float*)wsb;           wsb += 768 * 4;
    __hip_bfloat16* kattC = (__hip_bfloat16*)wsb;  wsb += 2 * nd * 2;
    __hip_bfloat16* mmsgC = (__hip_bfloat16*)wsb;  wsb += 2 * nd * 2;
    __hip_bfloat16* pooled= (__hip_bfloat16*)wsb;  wsb += nd * 2;
    int* counts  = (int*)wsb;                      wsb += (size_t)N_NODES * 4;
    int* row_ptr = (int*)wsb;                      wsb += (size_t)N_NODES * 4;
    int* cursor  = (int*)wsb;                      wsb += (size_t)N_NODES * 4;
    int* bsum    = (int*)wsb;                      wsb += 128 * 4;
    unsigned int* eidx = (unsigned int*)wsb;
    float* qbuf = out;   // q lives in d_out until final_mfma overwrites it

    hipMemsetAsync(counts, 0, (size_t)N_NODES * 4, stream);

    const int scan_blocks = (N_NODES + SCAN_B - 1) / SCAN_B;   // 98
    const int edge_blocks = (2 * E_EDGES + 255) / 256;         // 3125

    // CSR chain (independent of projections)
    hist_kernel<<<dim3(edge_blocks), dim3(256), 0, stream>>>(dst0, dst1, counts);
    scanA_kernel<<<dim3(scan_blocks), dim3(SCAN_B), 0, stream>>>(counts, row_ptr, bsum);
    scanB_kernel<<<dim3(1), dim3(64), 0, stream>>>(bsum, scan_blocks);
    scanC_kernel<<<dim3(scan_blocks), dim3(SCAN_B), 0, stream>>>(row_ptr, cursor, bsum);
    scatter_kernel<<<dim3(edge_blocks), dim3(256), 0, stream>>>(
        src0, dst0, src1, dst1, cursor, eidx);

    // Projections
    xcast_kernel<<<dim3((N_NODES * DIM / 4 + 255) / 256), dim3(256), 0, stream>>>(
        (const float4*)x, (__hip_bfloat162*)xb);
    fuse_weights<<<dim3(768), dim3(128), 0, stream>>>(
        Wk, bk, Wm, bm, Wq, bq, Wa, ba,
        Watt0, Wmsg0, Watt1, Wmsg1, prior0, prior1, Wt, bias);
    proj_mfma<<<dim3(N_NODES / 32), dim3(256), 0, stream>>>(
        xb, Wt, bias, kattC, mmsgC, qbuf);

    agg_kernel<<<dim3((N_NODES + 3) / 4), dim3(256), 0, stream>>>(
        (const __hip_bfloat162*)kattC, (const __hip_bfloat162*)mmsgC,
        (const float2*)qbuf, row_ptr, counts, eidx, (__hip_bfloat162*)pooled);

    final_mfma<<<dim3(N_NODES / 32), dim3(256), 0, stream>>>(
        pooled, Wt, bias, x, skip, gamma, beta, out);
}

// Round 6
// 415.288 us; speedup vs baseline: 2.4644x; 1.0376x over previous
//
#include <hip/hip_runtime.h>
#include <hip/hip_bf16.h>
#include <math.h>

#define N_NODES 100000
#define DIM 128
#define NH 8
#define NC 16
#define E_EDGES 400000
#define LN_EPS 1e-3f
#define SCAN_B 1024

typedef __attribute__((ext_vector_type(8))) short short8v;
typedef __attribute__((ext_vector_type(4))) float float4v;

__device__ __forceinline__ short bf16bits(float v) {
    __hip_bfloat16 b = __float2bfloat16(v);
    return *(short*)&b;
}

// ---------------- fused transposed weights (bf16) + fused biases -------------
// Wt[c][d], c in [0,768): sections of 128 cols:
//  0: Wk·BD(Watt0)·prior0/sqrt(C)   1: Wk·BD(Watt1)·prior1/sqrt(C)
//  2: Wm·BD(Wmsg0)                  3: Wm·BD(Wmsg1)
//  4: Wq                            5: Wa
__global__ __launch_bounds__(128) void fuse_weights(
    const float* __restrict__ Wk, const float* __restrict__ bk,
    const float* __restrict__ Wm, const float* __restrict__ bm,
    const float* __restrict__ Wq, const float* __restrict__ bq,
    const float* __restrict__ Wa, const float* __restrict__ ba,
    const float* __restrict__ Watt0, const float* __restrict__ Wmsg0,
    const float* __restrict__ Watt1, const float* __restrict__ Wmsg1,
    const float* __restrict__ prior0, const float* __restrict__ prior1,
    __hip_bfloat16* __restrict__ Wt, float* __restrict__ bias)
{
    const int c = blockIdx.x;        // 0..767
    const int d = threadIdx.x;       // 0..127
    const int sec = c >> 7, j = c & 127, h = j >> 4, l = j & 15;
    float v, b;
    if (sec == 4)      { v = Wq[d * DIM + j]; b = bq[j]; }
    else if (sec == 5) { v = Wa[d * DIM + j]; b = ba[j]; }
    else {
        const float* W1 = (sec < 2) ? Wk : Wm;
        const float* bs = (sec < 2) ? bk : bm;
        const float* W2 = (sec == 0) ? Watt0 : (sec == 1) ? Watt1
                          : (sec == 2) ? Wmsg0 : Wmsg1;
        float scale = (sec == 0) ? prior0[h] * 0.25f
                    : (sec == 1) ? prior1[h] * 0.25f : 1.f;
        float s = 0.f, sb = 0.f;
        #pragma unroll
        for (int kk = 0; kk < NC; ++kk) {
            float w2 = W2[h * 256 + kk * 16 + l];
            s  = fmaf(W1[d * DIM + h * 16 + kk], w2, s);
            sb = fmaf(bs[h * 16 + kk], w2, sb);
        }
        v = s * scale; b = sb * scale;
    }
    Wt[(size_t)c * DIM + d] = __float2bfloat16(v);
    if (d == 0) bias[c] = b;
}

// ---------------- proj: bf16 MFMA GEMM [N,128]@[128,640] ---------------------
// Block = 256 threads (4 waves), 32 rows. 5 sections x 128 cols; per section
// each wave computes 2 col-tiles, stages the 32x128 bf16 tile in LDS, then all
// 256 threads write it with coalesced 16B stores (fixes 32B-fragment writes).
__global__ __launch_bounds__(256) void proj_mfma(
    const float* __restrict__ x,             // [N][128] fp32
    const __hip_bfloat16* __restrict__ Wt,   // [768][128]
    const float* __restrict__ bias,          // [768]
    __hip_bfloat16* __restrict__ kattC,      // [2N][128]
    __hip_bfloat16* __restrict__ mmsgC,      // [2N][128]
    __hip_bfloat16* __restrict__ qb)         // [N][128]
{
    __shared__ short tile[32][DIM];
    const int wave = threadIdx.x >> 6, lane = threadIdx.x & 63;
    const int quad = lane >> 4, mcol = lane & 15;
    const int r0 = blockIdx.x * 32;

    // A fragments: fp32 x rows -> bf16 (fused cast, no separate xcast pass)
    short8v a0[4], a1[4];
    const float* xr0 = x + (size_t)(r0 + mcol) * DIM + quad * 8;
    const float* xr1 = xr0 + 16 * DIM;
    #pragma unroll
    for (int kb = 0; kb < 4; ++kb) {
        #pragma unroll
        for (int jj = 0; jj < 8; ++jj) {
            a0[kb][jj] = bf16bits(xr0[kb * 32 + jj]);
            a1[kb][jj] = bf16bits(xr1[kb * 32 + jj]);
        }
    }

    const int wrow = threadIdx.x >> 3;             // 0..31
    const int wcol = (threadIdx.x & 7) * 16;       // 0..112
    #pragma unroll
    for (int s = 0; s < 5; ++s) {
        #pragma unroll
        for (int tp = 0; tp < 2; ++tp) {
            const int ct = (wave + tp * 4) * 16;   // col within section
            const int c0 = s * 128 + ct;
            const short* wp = (const short*)Wt + (size_t)(c0 + mcol) * DIM + quad * 8;
            float4v acc0 = {0.f, 0.f, 0.f, 0.f};
            float4v acc1 = {0.f, 0.f, 0.f, 0.f};
            #pragma unroll
            for (int kb = 0; kb < 4; ++kb) {
                short8v bfr = *(const short8v*)(wp + kb * 32);
                acc0 = __builtin_amdgcn_mfma_f32_16x16x32_bf16(a0[kb], bfr, acc0, 0, 0, 0);
                acc1 = __builtin_amdgcn_mfma_f32_16x16x32_bf16(a1[kb], bfr, acc1, 0, 0, 0);
            }
            const float bcol = bias[c0 + mcol];
            const int cc = ct + mcol, rq = quad * 4;
            #pragma unroll
            for (int g = 0; g < 4; ++g) {
                tile[rq + g][cc]      = bf16bits(acc0[g] + bcol);
                tile[rq + 16 + g][cc] = bf16bits(acc1[g] + bcol);
            }
        }
        __syncthreads();
        __hip_bfloat16* dst =
            (s == 0) ? kattC + (size_t)r0 * DIM :
            (s == 1) ? kattC + ((size_t)N_NODES + r0) * DIM :
            (s == 2) ? mmsgC + (size_t)r0 * DIM :
            (s == 3) ? mmsgC + ((size_t)N_NODES + r0) * DIM :
                       qb    + (size_t)r0 * DIM;
        short* dp = (short*)dst + (size_t)wrow * DIM + wcol;
        *(short8v*)dp       = *(short8v*)&tile[wrow][wcol];
        *(short8v*)(dp + 8) = *(short8v*)&tile[wrow][wcol + 8];
        __syncthreads();
    }
}

// ---------------- CSR build ----------------
__global__ __launch_bounds__(256) void hist_kernel(
    const int* __restrict__ dst0, const int* __restrict__ dst1,
    int* __restrict__ counts)
{
    int e = blockIdx.x * 256 + threadIdx.x;
    if (e < E_EDGES) atomicAdd(&counts[dst0[e]], 1);
    int e1 = e - E_EDGES;
    if (e1 >= 0 && e1 < E_EDGES) atomicAdd(&counts[dst1[e1]], 1);
}

__global__ __launch_bounds__(SCAN_B) void scanA_kernel(
    const int* __restrict__ counts, int* __restrict__ row_ptr,
    int* __restrict__ bsum)
{
    __shared__ int buf[2][SCAN_B];
    int i = blockIdx.x * SCAN_B + threadIdx.x;
    int v = (i < N_NODES) ? counts[i] : 0;
    int cur = 0;
    buf[0][threadIdx.x] = v;
    __syncthreads();
    #pragma unroll
    for (int off = 1; off < SCAN_B; off <<= 1) {
        int t = buf[cur][threadIdx.x];
        int add = (threadIdx.x >= off) ? buf[cur][threadIdx.x - off] : 0;
        buf[cur ^ 1][threadIdx.x] = t + add;
        cur ^= 1;
        __syncthreads();
    }
    int inc = buf[cur][threadIdx.x];
    if (i < N_NODES) row_ptr[i] = inc - v;
    if (threadIdx.x == SCAN_B - 1) bsum[blockIdx.x] = inc;
}

// parallel exclusive scan of the (<=128) block sums, single block
__global__ __launch_bounds__(128) void scanB_kernel(int* __restrict__ bsum, int nblocks)
{
    __shared__ int buf[2][128];
    int t = threadIdx.x;
    int v = (t < nblocks) ? bsum[t] : 0;
    buf[0][t] = v;
    __syncthreads();
    int cur = 0;
    #pragma unroll
    for (int off = 1; off < 128; off <<= 1) {
        int a = buf[cur][t];
        if (t >= off) a += buf[cur][t - off];
        buf[cur ^ 1][t] = a;
        cur ^= 1;
        __syncthreads();
    }
    if (t < nblocks) bsum[t] = buf[cur][t] - v;   // exclusive
}

__global__ __launch_bounds__(SCAN_B) void scanC_kernel(
    int* __restrict__ row_ptr, int* __restrict__ cursor,
    const int* __restrict__ bsum)
{
    int i = blockIdx.x * SCAN_B + threadIdx.x;
    if (i < N_NODES) {
        int r = row_ptr[i] + bsum[blockIdx.x];
        row_ptr[i] = r;
        cursor[i] = r;
    }
}

__global__ __launch_bounds__(256) void scatter_kernel(
    const int* __restrict__ src0, const int* __restrict__ dst0,
    const int* __restrict__ src1, const int* __restrict__ dst1,
    int* __restrict__ cursor, unsigned int* __restrict__ eidx)
{
    int e = blockIdx.x * 256 + threadIdx.x;
    if (e < E_EDGES) {
        int d = dst0[e];
        int pos = atomicAdd(&cursor[d], 1);
        eidx[pos] = (unsigned int)src0[e];
    }
    int e1 = e - E_EDGES;
    if (e1 >= 0 && e1 < E_EDGES) {
        int d = dst1[e1];
        int pos = atomicAdd(&cursor[d], 1);
        eidx[pos] = (unsigned int)(src1[e1] + N_NODES);
    }
}

// ---------------- aggregation: one wave per node, no atomics -----------------
// Lane owns channel pair (2*lane, 2*lane+1). Writes gelu(pooled/denom) in bf16.
__global__ __launch_bounds__(256) void agg_kernel(
    const __hip_bfloat162* __restrict__ katt,   // [2N][64] channel pairs
    const __hip_bfloat162* __restrict__ mmsg,   // [2N][64]
    const __hip_bfloat162* __restrict__ qb2,    // [N][64]
    const int* __restrict__ row_ptr, const int* __restrict__ counts,
    const unsigned int* __restrict__ eidx,
    __hip_bfloat162* __restrict__ pooled2)      // [N][64]
{
    const int wave = threadIdx.x >> 6, lane = threadIdx.x & 63;
    const int n = blockIdx.x * 4 + wave;
    if (n >= N_NODES) return;
    const int start = row_ptr[n], cnt = counts[n];
    __hip_bfloat162 qv = qb2[(size_t)n * 64 + lane];
    const float qx = __bfloat162float(qv.x), qy = __bfloat162float(qv.y);

    float accx = 0.f, accy = 0.f, den = 0.f;
    int i = 0;
    for (; i + 2 <= cnt; i += 2) {
        unsigned int r0 = eidx[start + i];
        unsigned int r1 = eidx[start + i + 1];
        __hip_bfloat162 ka0 = katt[(size_t)r0 * 64 + lane];
        __hip_bfloat162 ka1 = katt[(size_t)r1 * 64 + lane];
        __hip_bfloat162 mg0 = mmsg[(size_t)r0 * 64 + lane];
        __hip_bfloat162 mg1 = mmsg[(size_t)r1 * 64 + lane];
        float p0 = fmaf(__bfloat162float(ka0.x), qx,
                        __bfloat162float(ka0.y) * qy);
        float p1 = fmaf(__bfloat162float(ka1.x), qx,
                        __bfloat162float(ka1.y) * qy);
        p0 += __shfl_xor(p0, 1, 64); p0 += __shfl_xor(p0, 2, 64); p0 += __shfl_xor(p0, 4, 64);
        p1 += __shfl_xor(p1, 1, 64); p1 += __shfl_xor(p1, 2, 64); p1 += __shfl_xor(p1, 4, 64);
        float e0 = __expf(p0), e1 = __expf(p1);
        accx = fmaf(e0, __bfloat162float(mg0.x), accx);
        accy = fmaf(e0, __bfloat162float(mg0.y), accy);
        accx = fmaf(e1, __bfloat162float(mg1.x), accx);
        accy = fmaf(e1, __bfloat162float(mg1.y), accy);
        den += e0 + e1;
    }
    if (i < cnt) {
        unsigned int r0 = eidx[start + i];
        __hip_bfloat162 ka0 = katt[(size_t)r0 * 64 + lane];
        __hip_bfloat162 mg0 = mmsg[(size_t)r0 * 64 + lane];
        float p0 = fmaf(__bfloat162float(ka0.x), qx,
                        __bfloat162float(ka0.y) * qy);
        p0 += __shfl_xor(p0, 1, 64); p0 += __shfl_xor(p0, 2, 64); p0 += __shfl_xor(p0, 4, 64);
        float e0 = __expf(p0);
        accx = fmaf(e0, __bfloat162float(mg0.x), accx);
        accy = fmaf(e0, __bfloat162float(mg0.y), accy);
        den += e0;
    }

    float vx = 0.f, vy = 0.f;
    if (den > 0.f) { vx = accx / den; vy = accy / den; }
    vx = 0.5f * vx * (1.f + erff(vx * 0.70710678118654752f));
    vy = 0.5f * vy * (1.f + erff(vy * 0.70710678118654752f));
    __hip_bfloat162 o; o.x = __float2bfloat16(vx); o.y = __float2bfloat16(vy);
    pooled2[(size_t)n * 64 + lane] = o;
}

// ---------------- final: MFMA GEMM(Wa) -> skip -> LayerNorm ------------------
__global__ __launch_bounds__(256) void final_mfma(
    const __hip_bfloat16* __restrict__ pooled,  // [N][128] bf16, gelu applied
    const __hip_bfloat16* __restrict__ Wt,      // [768][128]; rows 640.. = Wa^T
    const float* __restrict__ bias,             // [768]; 640.. = ba
    const float* __restrict__ x,
    const float* __restrict__ skip, const float* __restrict__ gamma,
    const float* __restrict__ beta, float* __restrict__ out)
{
    __shared__ float hs[32][DIM];
    const int wave = threadIdx.x >> 6, lane = threadIdx.x & 63;
    const int quad = lane >> 4, mcol = lane & 15;
    const int r0 = blockIdx.x * 32;

    short8v a0[4], a1[4];
    const short* pp0 = (const short*)pooled + (size_t)(r0 + mcol) * DIM + quad * 8;
    const short* pp1 = pp0 + 16 * DIM;
    #pragma unroll
    for (int kb = 0; kb < 4; ++kb) {
        a0[kb] = *(const short8v*)(pp0 + kb * 32);
        a1[kb] = *(const short8v*)(pp1 + kb * 32);
    }
    const float alpha = 1.f / (1.f + expf(-skip[0]));

    #pragma unroll
    for (int t = 0; t < 2; ++t) {
        const int c0 = wave * 32 + t * 16;
        const short* wp = (const short*)Wt + (size_t)(640 + c0 + mcol) * DIM + quad * 8;
        float4v acc0 = {0.f, 0.f, 0.f, 0.f};
        float4v acc1 = {0.f, 0.f, 0.f, 0.f};
        #pragma unroll
        for (int kb = 0; kb < 4; ++kb) {
            short8v bfr = *(const short8v*)(wp + kb * 32);
            acc0 = __builtin_amdgcn_mfma_f32_16x16x32_bf16(a0[kb], bfr, acc0, 0, 0, 0);
            acc1 = __builtin_amdgcn_mfma_f32_16x16x32_bf16(a1[kb], bfr, acc1, 0, 0, 0);
        }
        const float bcol = bias[640 + c0 + mcol];
        const int cc = c0 + mcol;
        const int rq = quad * 4;
        #pragma unroll
        for (int g = 0; g < 4; ++g) {
            int rA = rq + g, rB = rq + 16 + g;
            hs[rA][cc] = alpha * (acc0[g] + bcol)
                       + (1.f - alpha) * x[(size_t)(r0 + rA) * DIM + cc];
            hs[rB][cc] = alpha * (acc1[g] + bcol)
                       + (1.f - alpha) * x[(size_t)(r0 + rB) * DIM + cc];
        }
    }
    __syncthreads();

    float gam0 = gamma[lane], gam1 = gamma[lane + 64];
    float bet0 = beta[lane],  bet1 = beta[lane + 64];
    for (int r = wave; r < 32; r += 4) {
        int row = r0 + r;
        float v0 = hs[r][lane], v1 = hs[r][lane + 64];
        float s = v0 + v1, s2 = v0 * v0 + v1 * v1;
        #pragma unroll
        for (int off = 1; off < 64; off <<= 1) {
            s  += __shfl_xor(s,  off, 64);
            s2 += __shfl_xor(s2, off, 64);
        }
        float mu = s * (1.f / 128.f);
        float var = s2 * (1.f / 128.f) - mu * mu;
        float rstd = rsqrtf(var + LN_EPS);
        out[(size_t)row * DIM + lane]      = (v0 - mu) * rstd * gam0 + bet0;
        out[(size_t)row * DIM + lane + 64] = (v1 - mu) * rstd * gam1 + bet1;
    }
}

extern "C" void kernel_launch(void* const* d_in, const int* in_sizes, int n_in,
                              void* d_out, int out_size, void* d_ws, size_t ws_size,
                              hipStream_t stream) {
    const float* x     = (const float*)d_in[0];
    const int*   src0  = (const int*)d_in[1];
    const int*   dst0  = (const int*)d_in[2];
    const int*   src1  = (const int*)d_in[3];
    const int*   dst1  = (const int*)d_in[4];
    const float* Wk    = (const float*)d_in[5];
    const float* bk    = (const float*)d_in[6];
    const float* Wm    = (const float*)d_in[7];
    const float* bm    = (const float*)d_in[8];
    const float* Wq    = (const float*)d_in[9];
    const float* bq    = (const float*)d_in[10];
    const float* Wa    = (const float*)d_in[11];
    const float* ba    = (const float*)d_in[12];
    const float* Watt0 = (const float*)d_in[13];
    const float* Wmsg0 = (const float*)d_in[14];
    const float* Watt1 = (const float*)d_in[15];
    const float* Wmsg1 = (const float*)d_in[16];
    const float* prior0= (const float*)d_in[17];
    const float* prior1= (const float*)d_in[18];
    const float* skip  = (const float*)d_in[19];
    const float* gamma = (const float*)d_in[20];
    const float* beta  = (const float*)d_in[21];
    float* out = (float*)d_out;

    const size_t nd = (size_t)N_NODES * DIM;
    // Workspace (~158 MB):
    //   Wt [768*128 bf16] | bias [768 f32] | kattC [2nd bf16] | mmsgC [2nd bf16]
    //   | qb [nd bf16] | pooled [nd bf16] | counts/row_ptr/cursor [N i32]
    //   | bsum [128 i32] | eidx [2E u32]
    char* wsb = (char*)d_ws;
    __hip_bfloat16* Wt    = (__hip_bfloat16*)wsb;  wsb += (size_t)768 * DIM * 2;
    float* bias           = (float*)wsb;           wsb += 768 * 4;
    __hip_bfloat16* kattC = (__hip_bfloat16*)wsb;  wsb += 2 * nd * 2;
    __hip_bfloat16* mmsgC = (__hip_bfloat16*)wsb;  wsb += 2 * nd * 2;
    __hip_bfloat16* qb    = (__hip_bfloat16*)wsb;  wsb += nd * 2;
    __hip_bfloat16* pooled= (__hip_bfloat16*)wsb;  wsb += nd * 2;
    int* counts  = (int*)wsb;                      wsb += (size_t)N_NODES * 4;
    int* row_ptr = (int*)wsb;                      wsb += (size_t)N_NODES * 4;
    int* cursor  = (int*)wsb;                      wsb += (size_t)N_NODES * 4;
    int* bsum    = (int*)wsb;                      wsb += 128 * 4;
    unsigned int* eidx = (unsigned int*)wsb;

    hipMemsetAsync(counts, 0, (size_t)N_NODES * 4, stream);

    const int scan_blocks = (N_NODES + SCAN_B - 1) / SCAN_B;   // 98
    const int edge_blocks = (2 * E_EDGES + 255) / 256;         // 3125

    // CSR chain (independent of projections)
    hist_kernel<<<dim3(edge_blocks), dim3(256), 0, stream>>>(dst0, dst1, counts);
    scanA_kernel<<<dim3(scan_blocks), dim3(SCAN_B), 0, stream>>>(counts, row_ptr, bsum);
    scanB_kernel<<<dim3(1), dim3(128), 0, stream>>>(bsum, scan_blocks);
    scanC_kernel<<<dim3(scan_blocks), dim3(SCAN_B), 0, stream>>>(row_ptr, cursor, bsum);
    scatter_kernel<<<dim3(edge_blocks), dim3(256), 0, stream>>>(
        src0, dst0, src1, dst1, cursor, eidx);

    // Projections
    fuse_weights<<<dim3(768), dim3(128), 0, stream>>>(
        Wk, bk, Wm, bm, Wq, bq, Wa, ba,
        Watt0, Wmsg0, Watt1, Wmsg1, prior0, prior1, Wt, bias);
    proj_mfma<<<dim3(N_NODES / 32), dim3(256), 0, stream>>>(
        x, Wt, bias, kattC, mmsgC, qb);

    agg_kernel<<<dim3((N_NODES + 3) / 4), dim3(256), 0, stream>>>(
        (const __hip_bfloat162*)kattC, (const __hip_bfloat162*)mmsgC,
        (const __hip_bfloat162*)qb, row_ptr, counts, eidx,
        (__hip_bfloat162*)pooled);

    final_mfma<<<dim3(N_NODES / 32), dim3(256), 0, stream>>>(
        pooled, Wt, bias, x, skip, gamma, beta, out);
}